// Round 1
// baseline (4163.725 us; speedup 1.0000x reference)
//
#include <hip/hip_runtime.h>
#include <math.h>

#define DMODEL 1024
#define NHEADS 16
#define DHEAD  64
#define BATCH  2
#define SEQ    2048
#define NTOK   (BATCH*SEQ)          // 4096
#define WEL    (DMODEL*DMODEL)      // 1048576

// ---------------- workspace layout (bytes) ----------------
// [0,4096)           : scalar doubles
// [4096, +4*WEL)     : int8 ternary weights (Wq,Wk,Wv,Wo)
// Q / K / V          : fp64 [B,H,T,Dh] buffers, 33,554,432 B each
// attention output overwrites Q (same layout); out-proj recomputes z (no buffer)
#define OFF_TERN 4096
#define OFF_Q    (4096 + 4*WEL)                  // 4,198,400
#define OFF_K    (OFF_Q + 33554432)
#define OFF_V    (OFF_K + 33554432)
#define WS_NEED  ((size_t)OFF_V + 33554432)      // 104,861,696

// scalar indices (doubles): 0..3 absSum, 4..7 maskedSum, 8..11 maskCnt,
// 12..15 alpha, 16..19 delta, 20 maxabs-bits(ull), 21 scale

__global__ void k_zero_scalars(double* S) {
    if (threadIdx.x < 64) S[threadIdx.x] = 0.0;
}

__device__ __forceinline__ double block_reduce_sum(double v, double* red) {
    int tid = threadIdx.x;
    __syncthreads();
    red[tid] = v;
    __syncthreads();
    for (int s = 128; s > 0; s >>= 1) {
        if (tid < s) red[tid] += red[tid + s];
        __syncthreads();
    }
    return red[0];
}

__global__ __launch_bounds__(256) void k_abssum(
    const float* __restrict__ W0, const float* __restrict__ W1,
    const float* __restrict__ W2, const float* __restrict__ W3, double* S) {
    __shared__ double red[256];
    int w = blockIdx.y;
    const float* W = (w == 0) ? W0 : (w == 1) ? W1 : (w == 2) ? W2 : W3;
    double s = 0.0;
    for (int i = blockIdx.x * 256 + threadIdx.x; i < WEL; i += 256 * 256)
        s += fabs((double)W[i]);
    double bs = block_reduce_sum(s, red);
    if (threadIdx.x == 0) atomicAdd(&S[w], bs);
}

__global__ void k_delta(double* S) {
    int w = threadIdx.x;
    if (w < 4) S[16 + w] = 0.05 * S[w] / (double)WEL;
}

__global__ __launch_bounds__(256) void k_tern(
    const float* __restrict__ W0, const float* __restrict__ W1,
    const float* __restrict__ W2, const float* __restrict__ W3,
    signed char* __restrict__ tern, double* S) {
    __shared__ double red[256];
    int w = blockIdx.y;
    const float* W = (w == 0) ? W0 : (w == 1) ? W1 : (w == 2) ? W2 : W3;
    signed char* t = tern + (size_t)w * WEL;
    double delta = S[16 + w];
    double ms = 0.0, mc = 0.0;
    for (int i = blockIdx.x * 256 + threadIdx.x; i < WEL; i += 256 * 256) {
        float wv = W[i];
        double a = fabs((double)wv);
        bool m = a > delta;
        t[i] = m ? (wv > 0.0f ? (signed char)1 : (signed char)-1) : (signed char)0;
        if (m) { ms += a; mc += 1.0; }
    }
    double bms = block_reduce_sum(ms, red);
    double bmc = block_reduce_sum(mc, red);
    if (threadIdx.x == 0) { atomicAdd(&S[4 + w], bms); atomicAdd(&S[8 + w], bmc); }
}

__global__ void k_alpha(double* S) {
    int w = threadIdx.x;
    if (w < 4) S[12 + w] = S[4 + w] / fmax(S[8 + w], 1.0);
}

// ---------------- QKV projection: 64x64 tile, 4x4 per thread, fp64 ----------------
__global__ __launch_bounds__(256) void k_proj(
    const float* __restrict__ x, const signed char* __restrict__ tern,
    const float* __restrict__ bq, const float* __restrict__ bk,
    const float* __restrict__ bv,
    double* __restrict__ Q, double* __restrict__ K, double* __restrict__ V,
    const double* __restrict__ S) {
    int w = blockIdx.z;
    const signed char* t = tern + (size_t)w * WEL;
    const float* bias = (w == 0) ? bq : (w == 1) ? bk : bv;
    double* dst = (w == 0) ? Q : (w == 1) ? K : V;
    double alpha = S[12 + w];

    __shared__ double xs[64][33];
    __shared__ double ts[64][33];
    int tid = threadIdx.y * 16 + threadIdx.x;
    int tx = threadIdx.x, ty = threadIdx.y;
    int row0 = blockIdx.y * 64, col0 = blockIdx.x * 64;

    double acc[4][4];
#pragma unroll
    for (int i = 0; i < 4; i++)
#pragma unroll
        for (int u = 0; u < 4; u++) acc[i][u] = 0.0;

    for (int kb = 0; kb < DMODEL; kb += 32) {
        for (int i = tid; i < 64 * 32; i += 256) {
            int rr = i >> 5, kk = i & 31;
            xs[rr][kk] = (double)x[(size_t)(row0 + rr) * DMODEL + kb + kk];
            ts[rr][kk] = (double)t[(size_t)(col0 + rr) * DMODEL + kb + kk];
        }
        __syncthreads();
#pragma unroll
        for (int kk = 0; kk < 32; ++kk) {
            double a0 = xs[ty][kk], a1 = xs[ty + 16][kk],
                   a2 = xs[ty + 32][kk], a3 = xs[ty + 48][kk];
            double b0 = ts[tx][kk], b1 = ts[tx + 16][kk],
                   b2 = ts[tx + 32][kk], b3 = ts[tx + 48][kk];
            acc[0][0] += a0 * b0; acc[0][1] += a0 * b1; acc[0][2] += a0 * b2; acc[0][3] += a0 * b3;
            acc[1][0] += a1 * b0; acc[1][1] += a1 * b1; acc[1][2] += a1 * b2; acc[1][3] += a1 * b3;
            acc[2][0] += a2 * b0; acc[2][1] += a2 * b1; acc[2][2] += a2 * b2; acc[2][3] += a2 * b3;
            acc[3][0] += a3 * b0; acc[3][1] += a3 * b1; acc[3][2] += a3 * b2; acc[3][3] += a3 * b3;
        }
        __syncthreads();
    }
#pragma unroll
    for (int i = 0; i < 4; i++) {
        int n = row0 + ty + 16 * i;
        int b = n >> 11, tt = n & 2047;
#pragma unroll
        for (int u = 0; u < 4; u++) {
            int o = col0 + tx + 16 * u;
            int h = o >> 6, d = o & 63;
            double val = alpha * acc[i][u] + (double)bias[o];
            dst[(((size_t)(b * NHEADS + h) * SEQ) + tt) * DHEAD + d] = val;
        }
    }
}

// ---------------- fp64 flash attention; writes y over Q (same layout) ----------------
__global__ __launch_bounds__(256) void k_attn(double* __restrict__ Q,
                                              const double* __restrict__ K,
                                              const double* __restrict__ V) {
    __shared__ double qs[32][65];
    __shared__ double Kt[32][65];
    __shared__ double Vt[32][64];
    __shared__ double ps[32][33];

    int bh = blockIdx.y;
    int t0 = blockIdx.x * 32;
    int tid = threadIdx.x;
    int rt = tid >> 4, j = tid & 15;

    double* Qg = Q + (size_t)bh * SEQ * DHEAD;
    const double* Kg = K + (size_t)bh * SEQ * DHEAD;
    const double* Vg = V + (size_t)bh * SEQ * DHEAD;

    for (int i = tid; i < 32 * 64; i += 256)
        qs[i >> 6][i & 63] = Qg[(size_t)(t0 + (i >> 6)) * DHEAD + (i & 63)];

    double m0 = -INFINITY, m1 = -INFINITY, l0 = 0.0, l1 = 0.0;
    double acc0[4] = {0, 0, 0, 0}, acc1[4] = {0, 0, 0, 0};

    for (int s0 = 0; s0 < SEQ; s0 += 32) {
        __syncthreads();
        for (int i = tid; i < 32 * 64; i += 256) {
            int s = i >> 6, d = i & 63;
            Kt[s][d] = Kg[(size_t)(s0 + s) * DHEAD + d];
            Vt[s][d] = Vg[(size_t)(s0 + s) * DHEAD + d];
        }
        __syncthreads();

        double d00 = 0, d01 = 0, d10 = 0, d11 = 0;
#pragma unroll
        for (int d = 0; d < 64; ++d) {
            double q0 = qs[rt][d], q1 = qs[rt + 16][d];
            double k0 = Kt[2 * j][d], k1 = Kt[2 * j + 1][d];
            d00 += q0 * k0; d01 += q0 * k1; d10 += q1 * k0; d11 += q1 * k1;
        }
        double l00 = d00 * 0.125, l01 = d01 * 0.125;
        double l10 = d10 * 0.125, l11 = d11 * 0.125;

        double mt0 = fmax(l00, l01), mt1 = fmax(l10, l11);
#pragma unroll
        for (int off = 1; off < 16; off <<= 1) {
            mt0 = fmax(mt0, __shfl_xor(mt0, off, 16));
            mt1 = fmax(mt1, __shfl_xor(mt1, off, 16));
        }
        double mn0 = fmax(m0, mt0), mn1 = fmax(m1, mt1);
        double c0 = exp(m0 - mn0), c1 = exp(m1 - mn1);
        l0 *= c0; l1 *= c1;
#pragma unroll
        for (int u = 0; u < 4; u++) { acc0[u] *= c0; acc1[u] *= c1; }
        double p00 = exp(l00 - mn0), p01 = exp(l01 - mn0);
        double p10 = exp(l10 - mn1), p11 = exp(l11 - mn1);
        ps[rt][2 * j] = p00; ps[rt][2 * j + 1] = p01;
        ps[rt + 16][2 * j] = p10; ps[rt + 16][2 * j + 1] = p11;
        double sa = p00 + p01, sb = p10 + p11;
#pragma unroll
        for (int off = 1; off < 16; off <<= 1) {
            sa += __shfl_xor(sa, off, 16);
            sb += __shfl_xor(sb, off, 16);
        }
        l0 += sa; l1 += sb;
        m0 = mn0; m1 = mn1;
        __syncthreads();

        for (int s = 0; s < 32; ++s) {
            double p0 = ps[rt][s], p1 = ps[rt + 16][s];
#pragma unroll
            for (int u = 0; u < 4; u++) {
                double vv = Vt[s][j + 16 * u];
                acc0[u] += p0 * vv;
                acc1[u] += p1 * vv;
            }
        }
    }
    double i0 = 1.0 / l0, i1 = 1.0 / l1;
#pragma unroll
    for (int u = 0; u < 4; u++) {
        Qg[(size_t)(t0 + rt) * DHEAD + j + 16 * u] = acc0[u] * i0;
        Qg[(size_t)(t0 + rt + 16) * DHEAD + j + 16 * u] = acc1[u] * i1;
    }
}

// ---------------- output projection (mode 0: global max; mode 1: quantize) ----------
__global__ __launch_bounds__(256) void k_oproj(
    const double* __restrict__ Y, const signed char* __restrict__ tern,
    const float* __restrict__ bo, float* __restrict__ out,
    double* __restrict__ S, int mode) {
    const signed char* t = tern + 3 * (size_t)WEL;
    double alpha = S[15];

    __shared__ double ys[64][33];
    __shared__ double ts[64][33];
    __shared__ double redm[256];
    int tid = threadIdx.y * 16 + threadIdx.x;
    int tx = threadIdx.x, ty = threadIdx.y;
    int row0 = blockIdx.y * 64, col0 = blockIdx.x * 64;

    double acc[4][4];
#pragma unroll
    for (int i = 0; i < 4; i++)
#pragma unroll
        for (int u = 0; u < 4; u++) acc[i][u] = 0.0;

    for (int kb = 0; kb < DMODEL; kb += 32) {
        for (int i = tid; i < 64 * 32; i += 256) {
            int rr = i >> 5, kk = i & 31;
            int n = row0 + rr, c = kb + kk;
            int b = n >> 11, tt = n & 2047, h = c >> 6, d = c & 63;
            ys[rr][kk] = Y[(((size_t)(b * NHEADS + h) * SEQ) + tt) * DHEAD + d];
            ts[rr][kk] = (double)t[(size_t)(col0 + rr) * DMODEL + c];
        }
        __syncthreads();
#pragma unroll
        for (int kk = 0; kk < 32; ++kk) {
            double a0 = ys[ty][kk], a1 = ys[ty + 16][kk],
                   a2 = ys[ty + 32][kk], a3 = ys[ty + 48][kk];
            double b0 = ts[tx][kk], b1 = ts[tx + 16][kk],
                   b2 = ts[tx + 32][kk], b3 = ts[tx + 48][kk];
            acc[0][0] += a0 * b0; acc[0][1] += a0 * b1; acc[0][2] += a0 * b2; acc[0][3] += a0 * b3;
            acc[1][0] += a1 * b0; acc[1][1] += a1 * b1; acc[1][2] += a1 * b2; acc[1][3] += a1 * b3;
            acc[2][0] += a2 * b0; acc[2][1] += a2 * b1; acc[2][2] += a2 * b2; acc[2][3] += a2 * b3;
            acc[3][0] += a3 * b0; acc[3][1] += a3 * b1; acc[3][2] += a3 * b2; acc[3][3] += a3 * b3;
        }
        __syncthreads();
    }

    if (mode == 0) {
        double mx = 0.0;
#pragma unroll
        for (int i = 0; i < 4; i++)
#pragma unroll
            for (int u = 0; u < 4; u++) {
                int o = col0 + tx + 16 * u;
                double z = alpha * acc[i][u] + (double)bo[o];
                mx = fmax(mx, fabs(z));
            }
        redm[tid] = mx;
        __syncthreads();
        for (int s = 128; s > 0; s >>= 1) {
            if (tid < s) redm[tid] = fmax(redm[tid], redm[tid + s]);
            __syncthreads();
        }
        if (tid == 0)
            atomicMax((unsigned long long*)&S[20],
                      (unsigned long long)__double_as_longlong(redm[0]));
    } else {
        double scale = S[21];
        double inv = 1.0 / scale;
#pragma unroll
        for (int i = 0; i < 4; i++) {
            int n = row0 + ty + 16 * i;
#pragma unroll
            for (int u = 0; u < 4; u++) {
                int o = col0 + tx + 16 * u;
                double z = alpha * acc[i][u] + (double)bo[o];
                double r = rint(z * inv);
                r = fmin(fmax(r, -7.0), 7.0);
                out[(size_t)n * DMODEL + o] = (float)(r * scale);
            }
        }
    }
}

__global__ void k_scale(double* S) {
    unsigned long long bits = *((unsigned long long*)&S[20]);
    double mx = __longlong_as_double((long long)bits);
    S[21] = fmax(mx / 7.0, 1e-8);
}

extern "C" void kernel_launch(void* const* d_in, const int* in_sizes, int n_in,
                              void* d_out, int out_size, void* d_ws, size_t ws_size,
                              hipStream_t stream) {
    if (ws_size < WS_NEED) return;  // signal: output stays untouched

    const float* x  = (const float*)d_in[0];
    const float* Wq = (const float*)d_in[1];
    const float* bq = (const float*)d_in[2];
    const float* Wk = (const float*)d_in[3];
    const float* bk = (const float*)d_in[4];
    const float* Wv = (const float*)d_in[5];
    const float* bv = (const float*)d_in[6];
    const float* Wo = (const float*)d_in[7];
    const float* bo = (const float*)d_in[8];
    float* out = (float*)d_out;

    double* S = (double*)d_ws;
    signed char* tern = (signed char*)d_ws + OFF_TERN;
    double* Q = (double*)((char*)d_ws + OFF_Q);
    double* K = (double*)((char*)d_ws + OFF_K);
    double* V = (double*)((char*)d_ws + OFF_V);

    k_zero_scalars<<<1, 64, 0, stream>>>(S);
    k_abssum<<<dim3(256, 4), 256, 0, stream>>>(Wq, Wk, Wv, Wo, S);
    k_delta<<<1, 64, 0, stream>>>(S);
    k_tern<<<dim3(256, 4), 256, 0, stream>>>(Wq, Wk, Wv, Wo, tern, S);
    k_alpha<<<1, 64, 0, stream>>>(S);
    k_proj<<<dim3(16, 64, 3), dim3(16, 16), 0, stream>>>(x, tern, bq, bk, bv, Q, K, V, S);
    k_attn<<<dim3(SEQ / 32, BATCH * NHEADS), 256, 0, stream>>>(Q, K, V);
    k_oproj<<<dim3(16, 64), dim3(16, 16), 0, stream>>>(Q, tern, bo, out, S, 0);
    k_scale<<<1, 1, 0, stream>>>(S);
    k_oproj<<<dim3(16, 64), dim3(16, 16), 0, stream>>>(Q, tern, bo, out, S, 1);
}

// Round 3
// 2752.072 us; speedup vs baseline: 1.5129x; 1.5129x over previous
//
#include <hip/hip_runtime.h>
#include <math.h>

#define DMODEL 1024
#define NHEADS 16
#define DHEAD  64
#define BATCH  2
#define SEQ    2048
#define NTOK   (BATCH*SEQ)          // 4096
#define WEL    (DMODEL*DMODEL)      // 1048576

typedef double v4d __attribute__((ext_vector_type(4)));

// ---------------- workspace layout (bytes) ----------------
// [0,4096)           : scalar doubles
// [4096, +4*WEL)     : int8 ternary weights (Wq,Wk,Wv,Wo)
// Q / K / V          : fp64 [B,H,T,Dh] buffers, 33,554,432 B each
// attention output overwrites Q; out-proj z overwrites K (as Z [4096][1024])
#define OFF_TERN 4096
#define OFF_Q    (4096 + 4*WEL)
#define OFF_K    (OFF_Q + 33554432)
#define OFF_V    (OFF_K + 33554432)
#define WS_NEED  ((size_t)OFF_V + 33554432)

// scalar indices (doubles): 0..3 absSum, 4..7 maskedSum, 8..11 maskCnt,
// 12..15 alpha, 16..19 delta, 20 maxabs-bits(ull), 21 scale

__global__ void k_zero_scalars(double* S) {
    if (threadIdx.x < 64) S[threadIdx.x] = 0.0;
}

__device__ __forceinline__ double block_reduce_sum(double v, double* red) {
    int tid = threadIdx.x;
    __syncthreads();
    red[tid] = v;
    __syncthreads();
    for (int s = 128; s > 0; s >>= 1) {
        if (tid < s) red[tid] += red[tid + s];
        __syncthreads();
    }
    return red[0];
}

__global__ __launch_bounds__(256) void k_abssum(
    const float* __restrict__ W0, const float* __restrict__ W1,
    const float* __restrict__ W2, const float* __restrict__ W3, double* S) {
    __shared__ double red[256];
    int w = blockIdx.y;
    const float* W = (w == 0) ? W0 : (w == 1) ? W1 : (w == 2) ? W2 : W3;
    double s = 0.0;
    for (int i = blockIdx.x * 256 + threadIdx.x; i < WEL; i += 256 * 256)
        s += fabs((double)W[i]);
    double bs = block_reduce_sum(s, red);
    if (threadIdx.x == 0) atomicAdd(&S[w], bs);
}

__global__ void k_delta(double* S) {
    int w = threadIdx.x;
    if (w < 4) S[16 + w] = 0.05 * S[w] / (double)WEL;
}

__global__ __launch_bounds__(256) void k_tern(
    const float* __restrict__ W0, const float* __restrict__ W1,
    const float* __restrict__ W2, const float* __restrict__ W3,
    signed char* __restrict__ tern, double* S) {
    __shared__ double red[256];
    int w = blockIdx.y;
    const float* W = (w == 0) ? W0 : (w == 1) ? W1 : (w == 2) ? W2 : W3;
    signed char* t = tern + (size_t)w * WEL;
    double delta = S[16 + w];
    double ms = 0.0, mc = 0.0;
    for (int i = blockIdx.x * 256 + threadIdx.x; i < WEL; i += 256 * 256) {
        float wv = W[i];
        double a = fabs((double)wv);
        bool m = a > delta;
        t[i] = m ? (wv > 0.0f ? (signed char)1 : (signed char)-1) : (signed char)0;
        if (m) { ms += a; mc += 1.0; }
    }
    double bms = block_reduce_sum(ms, red);
    double bmc = block_reduce_sum(mc, red);
    if (threadIdx.x == 0) { atomicAdd(&S[4 + w], bms); atomicAdd(&S[8 + w], bmc); }
}

__global__ void k_alpha(double* S) {
    int w = threadIdx.x;
    if (w < 4) S[12 + w] = S[4 + w] / fmax(S[8 + w], 1.0);
}

// ---------------- QKV projection: 64x64 tile, 4x4 per thread, fp64 VALU ------------
__global__ __launch_bounds__(256) void k_proj(
    const float* __restrict__ x, const signed char* __restrict__ tern,
    const float* __restrict__ bq, const float* __restrict__ bk,
    const float* __restrict__ bv,
    double* __restrict__ Q, double* __restrict__ K, double* __restrict__ V,
    const double* __restrict__ S) {
    int w = blockIdx.z;
    const signed char* t = tern + (size_t)w * WEL;
    const float* bias = (w == 0) ? bq : (w == 1) ? bk : bv;
    double* dst = (w == 0) ? Q : (w == 1) ? K : V;
    double alpha = S[12 + w];

    __shared__ double xs[64][33];
    __shared__ double ts[64][33];
    int tid = threadIdx.y * 16 + threadIdx.x;
    int tx = threadIdx.x, ty = threadIdx.y;
    int row0 = blockIdx.y * 64, col0 = blockIdx.x * 64;

    double acc[4][4];
#pragma unroll
    for (int i = 0; i < 4; i++)
#pragma unroll
        for (int u = 0; u < 4; u++) acc[i][u] = 0.0;

    for (int kb = 0; kb < DMODEL; kb += 32) {
        for (int i = tid; i < 64 * 32; i += 256) {
            int rr = i >> 5, kk = i & 31;
            xs[rr][kk] = (double)x[(size_t)(row0 + rr) * DMODEL + kb + kk];
            ts[rr][kk] = (double)t[(size_t)(col0 + rr) * DMODEL + kb + kk];
        }
        __syncthreads();
#pragma unroll
        for (int kk = 0; kk < 32; ++kk) {
            double a0 = xs[ty][kk], a1 = xs[ty + 16][kk],
                   a2 = xs[ty + 32][kk], a3 = xs[ty + 48][kk];
            double b0 = ts[tx][kk], b1 = ts[tx + 16][kk],
                   b2 = ts[tx + 32][kk], b3 = ts[tx + 48][kk];
            acc[0][0] += a0 * b0; acc[0][1] += a0 * b1; acc[0][2] += a0 * b2; acc[0][3] += a0 * b3;
            acc[1][0] += a1 * b0; acc[1][1] += a1 * b1; acc[1][2] += a1 * b2; acc[1][3] += a1 * b3;
            acc[2][0] += a2 * b0; acc[2][1] += a2 * b1; acc[2][2] += a2 * b2; acc[2][3] += a2 * b3;
            acc[3][0] += a3 * b0; acc[3][1] += a3 * b1; acc[3][2] += a3 * b2; acc[3][3] += a3 * b3;
        }
        __syncthreads();
    }
#pragma unroll
    for (int i = 0; i < 4; i++) {
        int n = row0 + ty + 16 * i;
        int b = n >> 11, tt = n & 2047;
#pragma unroll
        for (int u = 0; u < 4; u++) {
            int o = col0 + tx + 16 * u;
            int h = o >> 6, d = o & 63;
            double val = alpha * acc[i][u] + (double)bias[o];
            dst[(((size_t)(b * NHEADS + h) * SEQ) + tt) * DHEAD + d] = val;
        }
    }
}

// ---------------- fp64 MFMA flash attention; writes y over Q ----------------
// Input frags (standard CDNA f64): A[m][k]: lane = m + 16k; B[k][n]: lane = n + 16k.
// C/D layout is NOT assumed: two probe MFMAs (D=A.B rank-1) recover the true
// (reg,lane)->(row,col) mapping at runtime; rowi[j]/coli are used everywhere.
__global__ __launch_bounds__(256) void k_attn(double* __restrict__ Q,
                                              const double* __restrict__ K,
                                              const double* __restrict__ V) {
    __shared__ double QA[4 * 16 * 64];
    __shared__ double KB[4 * 16 * 65];
    __shared__ double VB[4 * 4 * 65];

    int tid = threadIdx.x;
    int w = tid >> 6, l = tid & 63;
    int lm = l & 15, lk = l >> 4;
    int bh = blockIdx.y;
    int t0 = blockIdx.x * 64;

    // --- layout self-calibration probes ---
    // row probe: A[m][0]=m, B[0][n]=1  -> D[i][j]=i
    // col probe: A[m][0]=1, B[0][n]=n  -> D[i][j]=j
    v4d zz = (v4d){0.0, 0.0, 0.0, 0.0};
    double pa = (lk == 0) ? (double)lm : 0.0;
    double pb = (lk == 0) ? 1.0 : 0.0;
    v4d rowv = __builtin_amdgcn_mfma_f64_16x16x4f64(pa, pb, zz, 0, 0, 0);
    v4d colv = __builtin_amdgcn_mfma_f64_16x16x4f64(pb, pa, zz, 0, 0, 0);
    int rowi[4];
#pragma unroll
    for (int j = 0; j < 4; ++j) rowi[j] = (int)rowv[j];
    int coli = (int)colv[0];

    double* Qg = Q + (size_t)bh * SEQ * DHEAD;
    const double* Kg = K + (size_t)bh * SEQ * DHEAD;
    const double* Vg = V + (size_t)bh * SEQ * DHEAD;

    // stage Q A-frags once. global read coalesced (lane->d).
    for (int it = 0; it < 16; ++it) {
        int idx = it * 256 + tid;
        int r = idx >> 6, d = idx & 63;
        QA[(((r >> 4) << 4) + (d >> 2)) * 64 + ((d & 3) << 4) + (r & 15)] =
            Qg[(size_t)(t0 + r) * DHEAD + d];
    }

    double m_[4], l_[4];
    v4d Yacc[4];
#pragma unroll
    for (int j = 0; j < 4; j++) { m_[j] = -INFINITY; l_[j] = 0.0; }
#pragma unroll
    for (int u = 0; u < 4; u++) Yacc[u] = (v4d){0.0, 0.0, 0.0, 0.0};

    for (int s0 = 0; s0 < SEQ; s0 += 64) {
        // ---- stage K B-frags ----
        for (int it = 0; it < 16; ++it) {
            int idx = it * 256 + tid;
            int s = idx >> 6, d = idx & 63;
            KB[((s >> 4) * 16 + (d >> 2)) * 65 + ((d & 3) << 4) + (s & 15)] =
                Kg[(size_t)(s0 + s) * DHEAD + d];
        }
        __syncthreads();

        // ---- S = Q K^T (per wave: 16 rows x 64 cols) ----
        v4d Sacc[4];
#pragma unroll
        for (int c = 0; c < 4; c++) Sacc[c] = (v4d){0.0, 0.0, 0.0, 0.0};
#pragma unroll
        for (int ks = 0; ks < 16; ++ks) {
            double a = QA[(w * 16 + ks) * 64 + l];
#pragma unroll
            for (int c = 0; c < 4; ++c) {
                double b = KB[(c * 16 + ks) * 65 + l];
                Sacc[c] = __builtin_amdgcn_mfma_f64_16x16x4f64(a, b, Sacc[c], 0, 0, 0);
            }
        }

        // ---- online softmax (reg j = some row; within-row math only) ----
        double pj[4][4];
#pragma unroll
        for (int j = 0; j < 4; ++j) {
            double mt = fmax(fmax(Sacc[0][j], Sacc[1][j]), fmax(Sacc[2][j], Sacc[3][j])) * 0.125;
            mt = fmax(mt, __shfl_xor(mt, 1));
            mt = fmax(mt, __shfl_xor(mt, 2));
            mt = fmax(mt, __shfl_xor(mt, 4));
            mt = fmax(mt, __shfl_xor(mt, 8));
            double mn = fmax(m_[j], mt);
            double cc = exp(m_[j] - mn);
            m_[j] = mn;
            l_[j] *= cc;
#pragma unroll
            for (int u = 0; u < 4; ++u) Yacc[u][j] *= cc;
            double rs = 0.0;
#pragma unroll
            for (int c = 0; c < 4; ++c) {
                double p = exp(Sacc[c][j] * 0.125 - mn);
                pj[c][j] = p;
                rs += p;
            }
            rs += __shfl_xor(rs, 1);
            rs += __shfl_xor(rs, 2);
            rs += __shfl_xor(rs, 4);
            rs += __shfl_xor(rs, 8);
            l_[j] += rs;
        }
        __syncthreads();   // all waves done reading KB before P overwrites it

        // ---- write P as A-frags into KB (PA) using TRUE (row,col) ----
        // element (row rowi[j], s = 16c + coli): step = 4c + (coli>>2),
        // k = coli&3, lane = rowi[j] + 16*(coli&3)
#pragma unroll
        for (int c = 0; c < 4; ++c)
#pragma unroll
            for (int j = 0; j < 4; ++j)
                KB[(w * 16 + 4 * c + (coli >> 2)) * 65 + rowi[j] + ((coli & 3) << 4)] = pj[c][j];
        __syncthreads();

        // ---- PV in 4 chunks of 16 s-rows ----
        for (int ch = 0; ch < 4; ++ch) {
            for (int it = 0; it < 4; ++it) {
                int idx = it * 256 + tid;
                int sl = idx >> 6, d = idx & 63;
                VB[((sl >> 2) * 4 + (d >> 4)) * 65 + ((sl & 3) << 4) + (d & 15)] =
                    Vg[(size_t)(s0 + ch * 16 + sl) * DHEAD + d];
            }
            __syncthreads();
#pragma unroll
            for (int scl = 0; scl < 4; ++scl) {
                double a = KB[(w * 16 + ch * 4 + scl) * 65 + l];
#pragma unroll
                for (int u = 0; u < 4; ++u) {
                    double b = VB[(scl * 4 + u) * 65 + l];
                    Yacc[u] = __builtin_amdgcn_mfma_f64_16x16x4f64(a, b, Yacc[u], 0, 0, 0);
                }
            }
            __syncthreads();
        }
    }

    // ---- epilogue: y = Yacc / l, overwrite Q tile, TRUE (row,col) ----
#pragma unroll
    for (int j = 0; j < 4; ++j) {
        double inv = 1.0 / l_[j];
#pragma unroll
        for (int u = 0; u < 4; ++u)
            Qg[(size_t)(t0 + 16 * w + rowi[j]) * DHEAD + 16 * u + coli] = Yacc[u][j] * inv;
    }
}

// ---------------- output projection: single pass, z -> Z buffer + global max -------
__global__ __launch_bounds__(256) void k_oproj(
    const double* __restrict__ Y, const signed char* __restrict__ tern,
    const float* __restrict__ bo, double* __restrict__ Z,
    double* __restrict__ S) {
    const signed char* t = tern + 3 * (size_t)WEL;
    double alpha = S[15];

    __shared__ double ys[64][33];
    __shared__ double ts[64][33];
    __shared__ double redm[256];
    int tid = threadIdx.y * 16 + threadIdx.x;
    int tx = threadIdx.x, ty = threadIdx.y;
    int row0 = blockIdx.y * 64, col0 = blockIdx.x * 64;

    double acc[4][4];
#pragma unroll
    for (int i = 0; i < 4; i++)
#pragma unroll
        for (int u = 0; u < 4; u++) acc[i][u] = 0.0;

    for (int kb = 0; kb < DMODEL; kb += 32) {
        for (int i = tid; i < 64 * 32; i += 256) {
            int rr = i >> 5, kk = i & 31;
            int n = row0 + rr, c = kb + kk;
            int b = n >> 11, tt = n & 2047, h = c >> 6, d = c & 63;
            ys[rr][kk] = Y[(((size_t)(b * NHEADS + h) * SEQ) + tt) * DHEAD + d];
            ts[rr][kk] = (double)t[(size_t)(col0 + rr) * DMODEL + c];
        }
        __syncthreads();
#pragma unroll
        for (int kk = 0; kk < 32; ++kk) {
            double a0 = ys[ty][kk], a1 = ys[ty + 16][kk],
                   a2 = ys[ty + 32][kk], a3 = ys[ty + 48][kk];
            double b0 = ts[tx][kk], b1 = ts[tx + 16][kk],
                   b2 = ts[tx + 32][kk], b3 = ts[tx + 48][kk];
            acc[0][0] += a0 * b0; acc[0][1] += a0 * b1; acc[0][2] += a0 * b2; acc[0][3] += a0 * b3;
            acc[1][0] += a1 * b0; acc[1][1] += a1 * b1; acc[1][2] += a1 * b2; acc[1][3] += a1 * b3;
            acc[2][0] += a2 * b0; acc[2][1] += a2 * b1; acc[2][2] += a2 * b2; acc[2][3] += a2 * b3;
            acc[3][0] += a3 * b0; acc[3][1] += a3 * b1; acc[3][2] += a3 * b2; acc[3][3] += a3 * b3;
        }
        __syncthreads();
    }

    double mx = 0.0;
#pragma unroll
    for (int i = 0; i < 4; i++) {
        int n = row0 + ty + 16 * i;
#pragma unroll
        for (int u = 0; u < 4; u++) {
            int o = col0 + tx + 16 * u;
            double z = alpha * acc[i][u] + (double)bo[o];
            Z[(size_t)n * DMODEL + o] = z;
            mx = fmax(mx, fabs(z));
        }
    }
    redm[tid] = mx;
    __syncthreads();
    for (int s = 128; s > 0; s >>= 1) {
        if (tid < s) redm[tid] = fmax(redm[tid], redm[tid + s]);
        __syncthreads();
    }
    if (tid == 0)
        atomicMax((unsigned long long*)&S[20],
                  (unsigned long long)__double_as_longlong(redm[0]));
}

__global__ void k_scale(double* S) {
    unsigned long long bits = *((unsigned long long*)&S[20]);
    double mx = __longlong_as_double((long long)bits);
    S[21] = fmax(mx / 7.0, 1e-8);
}

__global__ __launch_bounds__(256) void k_quant(const double* __restrict__ Z,
                                               const double* __restrict__ S,
                                               float* __restrict__ out) {
    double scale = S[21];
    double inv = 1.0 / scale;
    int i = blockIdx.x * 256 + threadIdx.x;
    const int n = NTOK * DMODEL;
    for (; i < n; i += gridDim.x * 256) {
        double r = rint(Z[i] * inv);
        r = fmin(fmax(r, -7.0), 7.0);
        out[i] = (float)(r * scale);
    }
}

extern "C" void kernel_launch(void* const* d_in, const int* in_sizes, int n_in,
                              void* d_out, int out_size, void* d_ws, size_t ws_size,
                              hipStream_t stream) {
    if (ws_size < WS_NEED) return;

    const float* x  = (const float*)d_in[0];
    const float* Wq = (const float*)d_in[1];
    const float* bq = (const float*)d_in[2];
    const float* Wk = (const float*)d_in[3];
    const float* bk = (const float*)d_in[4];
    const float* Wv = (const float*)d_in[5];
    const float* bv = (const float*)d_in[6];
    const float* Wo = (const float*)d_in[7];
    const float* bo = (const float*)d_in[8];
    float* out = (float*)d_out;

    double* S = (double*)d_ws;
    signed char* tern = (signed char*)d_ws + OFF_TERN;
    double* Q = (double*)((char*)d_ws + OFF_Q);
    double* K = (double*)((char*)d_ws + OFF_K);
    double* V = (double*)((char*)d_ws + OFF_V);
    double* Z = K;   // K buffer is free after attention

    k_zero_scalars<<<1, 64, 0, stream>>>(S);
    k_abssum<<<dim3(256, 4), 256, 0, stream>>>(Wq, Wk, Wv, Wo, S);
    k_delta<<<1, 64, 0, stream>>>(S);
    k_tern<<<dim3(256, 4), 256, 0, stream>>>(Wq, Wk, Wv, Wo, tern, S);
    k_alpha<<<1, 64, 0, stream>>>(S);
    k_proj<<<dim3(16, 64, 3), dim3(16, 16), 0, stream>>>(x, tern, bq, bk, bv, Q, K, V, S);
    k_attn<<<dim3(SEQ / 64, BATCH * NHEADS), 256, 0, stream>>>(Q, K, V);
    k_oproj<<<dim3(16, 64), dim3(16, 16), 0, stream>>>(Q, tern, bo, Z, S);
    k_scale<<<1, 1, 0, stream>>>(S);
    k_quant<<<4096, 256, 0, stream>>>(Z, S, out);
}

// Round 4
// 1430.541 us; speedup vs baseline: 2.9106x; 1.9238x over previous
//
#include <hip/hip_runtime.h>
#include <math.h>

#define DMODEL 1024
#define NHEADS 16
#define DHEAD  64
#define BATCH  2
#define SEQ    2048
#define NTOK   (BATCH*SEQ)          // 4096
#define WEL    (DMODEL*DMODEL)      // 1048576
#define PLANE  ((size_t)NTOK*DMODEL)  // 4,194,304 bytes per digit plane

typedef double v4d __attribute__((ext_vector_type(4)));
typedef int    v4i __attribute__((ext_vector_type(4)));

// ---------------- workspace layout (bytes) ----------------
// S scalars | tern 4MB | XD (x digits, 5 planes, 20MB; later y digits)
// | QD (q digits 20MB; later Z fp64 32MB spans QD+KD) | KD (k digits 20MB)
// | V fp64 32MB
#define OFF_TERN 4096
#define OFF_XD   (OFF_TERN + 4*WEL)            // 4,198,400
#define OFF_QD   (OFF_XD + 5*4194304)          // 25,169,920
#define OFF_KD   (OFF_QD + 5*4194304)          // 46,141,440
#define OFF_V    (OFF_KD + 5*4194304)          // 67,112,960
#define WS_NEED  ((size_t)OFF_V + 33554432)    // 100,667,392

#define TWO36 68719476736.0   // 2^36

// scalar indices (doubles): 0..3 absSum, 4..7 maskedSum, 8..11 maskCnt,
// 12..15 alpha, 16..19 delta, 20 maxabs-bits(ull), 21 scale

__global__ void k_zero_scalars(double* S) {
    if (threadIdx.x < 64) S[threadIdx.x] = 0.0;
}

__device__ __forceinline__ double block_reduce_sum(double v, double* red) {
    int tid = threadIdx.x;
    __syncthreads();
    red[tid] = v;
    __syncthreads();
    for (int s = 128; s > 0; s >>= 1) {
        if (tid < s) red[tid] += red[tid + s];
        __syncthreads();
    }
    return red[0];
}

__global__ __launch_bounds__(256) void k_abssum(
    const float* __restrict__ W0, const float* __restrict__ W1,
    const float* __restrict__ W2, const float* __restrict__ W3, double* S) {
    __shared__ double red[256];
    int w = blockIdx.y;
    const float* W = (w == 0) ? W0 : (w == 1) ? W1 : (w == 2) ? W2 : W3;
    double s = 0.0;
    for (int i = blockIdx.x * 256 + threadIdx.x; i < WEL; i += 256 * 256)
        s += fabs((double)W[i]);
    double bs = block_reduce_sum(s, red);
    if (threadIdx.x == 0) atomicAdd(&S[w], bs);
}

__global__ void k_delta(double* S) {
    int w = threadIdx.x;
    if (w < 4) S[16 + w] = 0.05 * S[w] / (double)WEL;
}

__global__ __launch_bounds__(256) void k_tern(
    const float* __restrict__ W0, const float* __restrict__ W1,
    const float* __restrict__ W2, const float* __restrict__ W3,
    signed char* __restrict__ tern, double* S) {
    __shared__ double red[256];
    int w = blockIdx.y;
    const float* W = (w == 0) ? W0 : (w == 1) ? W1 : (w == 2) ? W2 : W3;
    signed char* t = tern + (size_t)w * WEL;
    double delta = S[16 + w];
    double ms = 0.0, mc = 0.0;
    for (int i = blockIdx.x * 256 + threadIdx.x; i < WEL; i += 256 * 256) {
        float wv = W[i];
        double a = fabs((double)wv);
        bool m = a > delta;
        t[i] = m ? (wv > 0.0f ? (signed char)1 : (signed char)-1) : (signed char)0;
        if (m) { ms += a; mc += 1.0; }
    }
    double bms = block_reduce_sum(ms, red);
    double bmc = block_reduce_sum(mc, red);
    if (threadIdx.x == 0) { atomicAdd(&S[4 + w], bms); atomicAdd(&S[8 + w], bmc); }
}

__global__ void k_alpha(double* S) {
    int w = threadIdx.x;
    if (w < 4) S[12 + w] = S[4 + w] / fmax(S[8 + w], 1.0);
}

// ---------------- x -> 5 signed-i8 digit planes (exact: x*2^36 fits 40 bits) -------
__global__ __launch_bounds__(256) void k_digx(const float* __restrict__ x,
                                              signed char* __restrict__ XD) {
    int g = blockIdx.x * 256 + threadIdx.x;    // one group of 4 elements
    const int NG = NTOK * DMODEL / 4;
    if (g >= NG) return;
    float4 f = ((const float4*)x)[g];
    double vals[4] = {f.x, f.y, f.z, f.w};
    unsigned int p[5] = {0, 0, 0, 0, 0};
#pragma unroll
    for (int e = 0; e < 4; ++e) {
        long X = llrint(vals[e] * TWO36);
        const long LIM = (1L << 39) - 1;
        X = (X > LIM) ? LIM : (X < -LIM ? -LIM : X);
#pragma unroll
        for (int i = 0; i < 5; ++i) {
            signed char di = (signed char)X;
            X = (X - di) >> 8;
            p[i] |= ((unsigned int)(unsigned char)di) << (8 * e);
        }
    }
#pragma unroll
    for (int i = 0; i < 5; ++i)
        ((unsigned int*)(XD + (size_t)i * PLANE))[g] = p[i];
}

// ---------------- QKV projection via i8 MFMA over 5 digit planes -------------------
// Block: 128(M) x 64(N); 4 waves 2x2, wave tile 64x32 = 8 (16x16) MFMA tiles.
// Digit-outer: i32 acc exact over K=1024, then Facc += 2^(8d-36) * i32.
// q,k outputs digitized (5 planes); v output fp64 [B,H,T,Dh].
__global__ __launch_bounds__(256) void k_proji8(
    const signed char* __restrict__ XD, const signed char* __restrict__ tern,
    const float* __restrict__ bq, const float* __restrict__ bk,
    const float* __restrict__ bv,
    signed char* __restrict__ QD, signed char* __restrict__ KD,
    double* __restrict__ V, const double* __restrict__ S) {
    int w = blockIdx.z;
    const signed char* B = tern + (size_t)w * WEL;
    const float* bias = (w == 0) ? bq : (w == 1) ? bk : bv;
    double alpha = S[12 + w];

    __shared__ signed char As[128 * 144];
    __shared__ signed char Bs[64 * 144];

    int tid = threadIdx.x;
    int wv = tid >> 6, l = tid & 63, lm = l & 15, lk = l >> 4;
    int wy = wv >> 1, wx = wv & 1;
    int row0 = blockIdx.x * 128, col0 = blockIdx.y * 64;

    // C/D layout probe (i32): D[i][j]=i then D[i][j]=j via rank-1 products
    v4i zz4 = {0, 0, 0, 0};
    long pa = (lk == 0) ? (long)lm : 0L;
    long pb = (lk == 0) ? 1L : 0L;
    v4i rowv = __builtin_amdgcn_mfma_i32_16x16x32_i8(pa, pb, zz4, 0, 0, 0);
    v4i colv = __builtin_amdgcn_mfma_i32_16x16x32_i8(pb, pa, zz4, 0, 0, 0);
    int rowi[4];
#pragma unroll
    for (int j = 0; j < 4; ++j) rowi[j] = rowv[j];
    int coli = colv[0];

    v4d Facc[8];
#pragma unroll
    for (int t = 0; t < 8; ++t) Facc[t] = (v4d){0.0, 0.0, 0.0, 0.0};

    const double DW[5] = {0x1p-36, 0x1p-28, 0x1p-20, 0x1p-12, 0x1p-4};

    for (int d = 0; d < 5; ++d) {
        const signed char* Ad = XD + (size_t)d * PLANE;
        v4i Iacc[8];
#pragma unroll
        for (int t = 0; t < 8; ++t) Iacc[t] = (v4i){0, 0, 0, 0};

        for (int k0 = 0; k0 < DMODEL; k0 += 128) {
            __syncthreads();
            {   // stage A: 128 rows x 128 bytes
                int r = tid >> 1, hf = tid & 1;
                const int4* src = (const int4*)(Ad + (size_t)(row0 + r) * DMODEL + k0 + hf * 64);
                int4* dst = (int4*)(As + r * 144 + hf * 64);
                dst[0] = src[0]; dst[1] = src[1]; dst[2] = src[2]; dst[3] = src[3];
            }
            {   // stage B: 64 rows x 128 bytes
                int r = tid >> 2, q = tid & 3;
                const int4* src = (const int4*)(B + (size_t)(col0 + r) * DMODEL + k0 + q * 32);
                int4* dst = (int4*)(Bs + r * 144 + q * 32);
                dst[0] = src[0]; dst[1] = src[1];
            }
            __syncthreads();
#pragma unroll
            for (int ks = 0; ks < 4; ++ks) {
                long av[4], bv2[2];
#pragma unroll
                for (int mt = 0; mt < 4; ++mt)
                    av[mt] = *(const long*)(As + (wy * 64 + mt * 16 + lm) * 144 + ks * 32 + 8 * lk);
#pragma unroll
                for (int nt = 0; nt < 2; ++nt)
                    bv2[nt] = *(const long*)(Bs + (wx * 32 + nt * 16 + lm) * 144 + ks * 32 + 8 * lk);
#pragma unroll
                for (int mt = 0; mt < 4; ++mt)
#pragma unroll
                    for (int nt = 0; nt < 2; ++nt)
                        Iacc[mt * 2 + nt] = __builtin_amdgcn_mfma_i32_16x16x32_i8(
                            av[mt], bv2[nt], Iacc[mt * 2 + nt], 0, 0, 0);
            }
        }
        double wd = DW[d];
#pragma unroll
        for (int t = 0; t < 8; ++t)
#pragma unroll
            for (int j = 0; j < 4; ++j) Facc[t][j] += wd * (double)Iacc[t][j];
    }

    // epilogue
#pragma unroll
    for (int t = 0; t < 8; ++t) {
#pragma unroll
        for (int j = 0; j < 4; ++j) {
            int rl = wy * 64 + (t >> 1) * 16 + rowi[j];
            int cl = wx * 32 + (t & 1) * 16 + coli;
            int n = row0 + rl, c = col0 + cl;
            double v = alpha * Facc[t][j] + (double)bias[c];
            if (w == 2) {
                int b = n >> 11, tt = n & 2047, h = c >> 6, dd = c & 63;
                V[(((size_t)(b * NHEADS + h) * SEQ) + tt) * DHEAD + dd] = v;
            } else {
                signed char* P = (w == 0) ? QD : KD;
                long X = llrint(v * TWO36);
#pragma unroll
                for (int i = 0; i < 5; ++i) {
                    signed char di = (signed char)X;
                    X = (X - di) >> 8;
                    P[(size_t)i * PLANE + (size_t)n * DMODEL + c] = di;
                }
            }
        }
    }
}

// ---------------- fp64 MFMA flash attention; Q,K from digit planes; y -> digits ----
__global__ __launch_bounds__(256) void k_attn(const signed char* __restrict__ QD,
                                              const signed char* __restrict__ KD,
                                              const double* __restrict__ V,
                                              signed char* __restrict__ YD) {
    __shared__ double QA[4 * 16 * 64];
    __shared__ double KB[4 * 16 * 65];
    __shared__ double VB[4 * 4 * 65];

    int tid = threadIdx.x;
    int w = tid >> 6, l = tid & 63;
    int lm = l & 15, lk = l >> 4;
    int bh = blockIdx.y;
    int t0 = blockIdx.x * 64;
    int b = bh >> 4, h = bh & 15;
    size_t nrow0 = (size_t)b * SEQ;      // token base for this batch
    int cbase = h * 64;

    // f64 C/D layout probes
    v4d zz = (v4d){0.0, 0.0, 0.0, 0.0};
    double pa = (lk == 0) ? (double)lm : 0.0;
    double pb = (lk == 0) ? 1.0 : 0.0;
    v4d rowv = __builtin_amdgcn_mfma_f64_16x16x4f64(pa, pb, zz, 0, 0, 0);
    v4d colv = __builtin_amdgcn_mfma_f64_16x16x4f64(pb, pa, zz, 0, 0, 0);
    int rowi[4];
#pragma unroll
    for (int j = 0; j < 4; ++j) rowi[j] = (int)rowv[j];
    int coli = (int)colv[0];

    const double* Vg = V + (size_t)bh * SEQ * DHEAD;

    // ---- stage Q tile (64 t x 64 d) from digit planes ----
    for (int it = 0; it < 4; ++it) {
        int g = it * 256 + tid;            // 1024 groups of 4 d-bytes
        int r = g >> 4, dd = (g & 15) * 4;
        size_t a = (nrow0 + t0 + r) * DMODEL + cbase + dd;
        int u0 = *(const int*)(QD + 0 * PLANE + a);
        int u1 = *(const int*)(QD + 1 * PLANE + a);
        int u2 = *(const int*)(QD + 2 * PLANE + a);
        int u3 = *(const int*)(QD + 3 * PLANE + a);
        int u4 = *(const int*)(QD + 4 * PLANE + a);
#pragma unroll
        for (int e = 0; e < 4; ++e) {
            int b0 = (int)(signed char)(u0 >> (8 * e));
            int b1 = (int)(signed char)(u1 >> (8 * e));
            int b2 = (int)(signed char)(u2 >> (8 * e));
            int b3 = (int)(signed char)(u3 >> (8 * e));
            int b4 = (int)(signed char)(u4 >> (8 * e));
            double v = ((double)(b0 + (b1 << 8) + (b2 << 16)) +
                        (double)b3 * 16777216.0 + (double)b4 * 4294967296.0) * 0x1p-36;
            int d = dd + e;
            QA[(((r >> 4) << 4) + (d >> 2)) * 64 + ((d & 3) << 4) + (r & 15)] = v;
        }
    }

    double m_[4], l_[4];
    v4d Yacc[4];
#pragma unroll
    for (int j = 0; j < 4; j++) { m_[j] = -INFINITY; l_[j] = 0.0; }
#pragma unroll
    for (int u = 0; u < 4; u++) Yacc[u] = (v4d){0.0, 0.0, 0.0, 0.0};

    for (int s0 = 0; s0 < SEQ; s0 += 64) {
        __syncthreads();
        // ---- stage K tile from digit planes into B-frag layout ----
        for (int it = 0; it < 4; ++it) {
            int g = it * 256 + tid;
            int s = g >> 4, dd = (g & 15) * 4;
            size_t a = (nrow0 + s0 + s) * DMODEL + cbase + dd;
            int u0 = *(const int*)(KD + 0 * PLANE + a);
            int u1 = *(const int*)(KD + 1 * PLANE + a);
            int u2 = *(const int*)(KD + 2 * PLANE + a);
            int u3 = *(const int*)(KD + 3 * PLANE + a);
            int u4 = *(const int*)(KD + 4 * PLANE + a);
#pragma unroll
            for (int e = 0; e < 4; ++e) {
                int b0 = (int)(signed char)(u0 >> (8 * e));
                int b1 = (int)(signed char)(u1 >> (8 * e));
                int b2 = (int)(signed char)(u2 >> (8 * e));
                int b3 = (int)(signed char)(u3 >> (8 * e));
                int b4 = (int)(signed char)(u4 >> (8 * e));
                double v = ((double)(b0 + (b1 << 8) + (b2 << 16)) +
                            (double)b3 * 16777216.0 + (double)b4 * 4294967296.0) * 0x1p-36;
                int d = dd + e;
                KB[((s >> 4) * 16 + (d >> 2)) * 65 + ((d & 3) << 4) + (s & 15)] = v;
            }
        }
        __syncthreads();

        // ---- S = Q K^T ----
        v4d Sacc[4];
#pragma unroll
        for (int c = 0; c < 4; c++) Sacc[c] = (v4d){0.0, 0.0, 0.0, 0.0};
#pragma unroll
        for (int ks = 0; ks < 16; ++ks) {
            double a = QA[(w * 16 + ks) * 64 + l];
#pragma unroll
            for (int c = 0; c < 4; ++c) {
                double bq_ = KB[(c * 16 + ks) * 65 + l];
                Sacc[c] = __builtin_amdgcn_mfma_f64_16x16x4f64(a, bq_, Sacc[c], 0, 0, 0);
            }
        }

        // ---- online softmax ----
        double pj[4][4];
#pragma unroll
        for (int j = 0; j < 4; ++j) {
            double mt = fmax(fmax(Sacc[0][j], Sacc[1][j]), fmax(Sacc[2][j], Sacc[3][j])) * 0.125;
            mt = fmax(mt, __shfl_xor(mt, 1));
            mt = fmax(mt, __shfl_xor(mt, 2));
            mt = fmax(mt, __shfl_xor(mt, 4));
            mt = fmax(mt, __shfl_xor(mt, 8));
            double mn = fmax(m_[j], mt);
            double cc = exp(m_[j] - mn);
            m_[j] = mn;
            l_[j] *= cc;
#pragma unroll
            for (int u = 0; u < 4; ++u) Yacc[u][j] *= cc;
            double rs = 0.0;
#pragma unroll
            for (int c = 0; c < 4; ++c) {
                double p = exp(Sacc[c][j] * 0.125 - mn);
                pj[c][j] = p;
                rs += p;
            }
            rs += __shfl_xor(rs, 1);
            rs += __shfl_xor(rs, 2);
            rs += __shfl_xor(rs, 4);
            rs += __shfl_xor(rs, 8);
            l_[j] += rs;
        }
        __syncthreads();

        // ---- write P as A-frags into KB using probed (row,col) ----
#pragma unroll
        for (int c = 0; c < 4; ++c)
#pragma unroll
            for (int j = 0; j < 4; ++j)
                KB[(w * 16 + 4 * c + (coli >> 2)) * 65 + rowi[j] + ((coli & 3) << 4)] = pj[c][j];
        __syncthreads();

        // ---- PV in 4 chunks of 16 s-rows ----
        for (int ch = 0; ch < 4; ++ch) {
            for (int it = 0; it < 4; ++it) {
                int idx = it * 256 + tid;
                int sl = idx >> 6, d = idx & 63;
                VB[((sl >> 2) * 4 + (d >> 4)) * 65 + ((sl & 3) << 4) + (d & 15)] =
                    Vg[(size_t)(s0 + ch * 16 + sl) * DHEAD + d];
            }
            __syncthreads();
#pragma unroll
            for (int scl = 0; scl < 4; ++scl) {
                double a = KB[(w * 16 + ch * 4 + scl) * 65 + l];
#pragma unroll
                for (int u = 0; u < 4; ++u) {
                    double bb = VB[(scl * 4 + u) * 65 + l];
                    Yacc[u] = __builtin_amdgcn_mfma_f64_16x16x4f64(a, bb, Yacc[u], 0, 0, 0);
                }
            }
            __syncthreads();
        }
    }

    // ---- epilogue: y -> digit planes (token/channel layout) ----
#pragma unroll
    for (int j = 0; j < 4; ++j) {
        double inv = 1.0 / l_[j];
        size_t n = nrow0 + t0 + 16 * w + rowi[j];
#pragma unroll
        for (int u = 0; u < 4; ++u) {
            double y = Yacc[u][j] * inv;
            int c = cbase + 16 * u + coli;
            long X = llrint(y * TWO36);
#pragma unroll
            for (int i = 0; i < 5; ++i) {
                signed char di = (signed char)X;
                X = (X - di) >> 8;
                YD[(size_t)i * PLANE + n * DMODEL + c] = di;
            }
        }
    }
}

// ---------------- output projection via i8 MFMA; z -> Z fp64 + global max ----------
__global__ __launch_bounds__(256) void k_oproji8(
    const signed char* __restrict__ YD, const signed char* __restrict__ tern,
    const float* __restrict__ bo, double* __restrict__ Z, double* __restrict__ S) {
    const signed char* B = tern + 3 * (size_t)WEL;
    double alpha = S[15];

    __shared__ signed char As[128 * 144];
    __shared__ signed char Bs[64 * 144];
    __shared__ double redm[256];

    int tid = threadIdx.x;
    int wv = tid >> 6, l = tid & 63, lm = l & 15, lk = l >> 4;
    int wy = wv >> 1, wx = wv & 1;
    int row0 = blockIdx.x * 128, col0 = blockIdx.y * 64;

    v4i zz4 = {0, 0, 0, 0};
    long pa = (lk == 0) ? (long)lm : 0L;
    long pb = (lk == 0) ? 1L : 0L;
    v4i rowv = __builtin_amdgcn_mfma_i32_16x16x32_i8(pa, pb, zz4, 0, 0, 0);
    v4i colv = __builtin_amdgcn_mfma_i32_16x16x32_i8(pb, pa, zz4, 0, 0, 0);
    int rowi[4];
#pragma unroll
    for (int j = 0; j < 4; ++j) rowi[j] = rowv[j];
    int coli = colv[0];

    v4d Facc[8];
#pragma unroll
    for (int t = 0; t < 8; ++t) Facc[t] = (v4d){0.0, 0.0, 0.0, 0.0};

    const double DW[5] = {0x1p-36, 0x1p-28, 0x1p-20, 0x1p-12, 0x1p-4};

    for (int d = 0; d < 5; ++d) {
        const signed char* Ad = YD + (size_t)d * PLANE;
        v4i Iacc[8];
#pragma unroll
        for (int t = 0; t < 8; ++t) Iacc[t] = (v4i){0, 0, 0, 0};

        for (int k0 = 0; k0 < DMODEL; k0 += 128) {
            __syncthreads();
            {
                int r = tid >> 1, hf = tid & 1;
                const int4* src = (const int4*)(Ad + (size_t)(row0 + r) * DMODEL + k0 + hf * 64);
                int4* dst = (int4*)(As + r * 144 + hf * 64);
                dst[0] = src[0]; dst[1] = src[1]; dst[2] = src[2]; dst[3] = src[3];
            }
            {
                int r = tid >> 2, q = tid & 3;
                const int4* src = (const int4*)(B + (size_t)(col0 + r) * DMODEL + k0 + q * 32);
                int4* dst = (int4*)(Bs + r * 144 + q * 32);
                dst[0] = src[0]; dst[1] = src[1];
            }
            __syncthreads();
#pragma unroll
            for (int ks = 0; ks < 4; ++ks) {
                long av[4], bv2[2];
#pragma unroll
                for (int mt = 0; mt < 4; ++mt)
                    av[mt] = *(const long*)(As + (wy * 64 + mt * 16 + lm) * 144 + ks * 32 + 8 * lk);
#pragma unroll
                for (int nt = 0; nt < 2; ++nt)
                    bv2[nt] = *(const long*)(Bs + (wx * 32 + nt * 16 + lm) * 144 + ks * 32 + 8 * lk);
#pragma unroll
                for (int mt = 0; mt < 4; ++mt)
#pragma unroll
                    for (int nt = 0; nt < 2; ++nt)
                        Iacc[mt * 2 + nt] = __builtin_amdgcn_mfma_i32_16x16x32_i8(
                            av[mt], bv2[nt], Iacc[mt * 2 + nt], 0, 0, 0);
            }
        }
        double wd = DW[d];
#pragma unroll
        for (int t = 0; t < 8; ++t)
#pragma unroll
            for (int j = 0; j < 4; ++j) Facc[t][j] += wd * (double)Iacc[t][j];
    }

    double mx = 0.0;
#pragma unroll
    for (int t = 0; t < 8; ++t) {
#pragma unroll
        for (int j = 0; j < 4; ++j) {
            int rl = wy * 64 + (t >> 1) * 16 + rowi[j];
            int cl = wx * 32 + (t & 1) * 16 + coli;
            int n = row0 + rl, c = col0 + cl;
            double v = alpha * Facc[t][j] + (double)bo[c];
            Z[(size_t)n * DMODEL + c] = v;
            mx = fmax(mx, fabs(v));
        }
    }
    redm[tid] = mx;
    __syncthreads();
    for (int s = 128; s > 0; s >>= 1) {
        if (tid < s) redm[tid] = fmax(redm[tid], redm[tid + s]);
        __syncthreads();
    }
    if (tid == 0)
        atomicMax((unsigned long long*)&S[20],
                  (unsigned long long)__double_as_longlong(redm[0]));
}

__global__ void k_scale(double* S) {
    unsigned long long bits = *((unsigned long long*)&S[20]);
    double mx = __longlong_as_double((long long)bits);
    S[21] = fmax(mx / 7.0, 1e-8);
}

__global__ __launch_bounds__(256) void k_quant(const double* __restrict__ Z,
                                               const double* __restrict__ S,
                                               float* __restrict__ out) {
    double scale = S[21];
    double inv = 1.0 / scale;
    int i = blockIdx.x * 256 + threadIdx.x;
    const int n = NTOK * DMODEL;
    for (; i < n; i += gridDim.x * 256) {
        double r = rint(Z[i] * inv);
        r = fmin(fmax(r, -7.0), 7.0);
        out[i] = (float)(r * scale);
    }
}

extern "C" void kernel_launch(void* const* d_in, const int* in_sizes, int n_in,
                              void* d_out, int out_size, void* d_ws, size_t ws_size,
                              hipStream_t stream) {
    if (ws_size < WS_NEED) return;

    const float* x  = (const float*)d_in[0];
    const float* Wq = (const float*)d_in[1];
    const float* bq = (const float*)d_in[2];
    const float* Wk = (const float*)d_in[3];
    const float* bk = (const float*)d_in[4];
    const float* Wv = (const float*)d_in[5];
    const float* bv = (const float*)d_in[6];
    const float* Wo = (const float*)d_in[7];
    const float* bo = (const float*)d_in[8];
    float* out = (float*)d_out;

    double* S = (double*)d_ws;
    signed char* tern = (signed char*)d_ws + OFF_TERN;
    signed char* XD = (signed char*)d_ws + OFF_XD;   // x digits; later y digits
    signed char* QD = (signed char*)d_ws + OFF_QD;
    signed char* KD = (signed char*)d_ws + OFF_KD;
    double* V = (double*)((char*)d_ws + OFF_V);
    double* Z = (double*)((char*)d_ws + OFF_QD);     // QD/KD region free after attn

    k_zero_scalars<<<1, 64, 0, stream>>>(S);
    k_abssum<<<dim3(256, 4), 256, 0, stream>>>(Wq, Wk, Wv, Wo, S);
    k_delta<<<1, 64, 0, stream>>>(S);
    k_tern<<<dim3(256, 4), 256, 0, stream>>>(Wq, Wk, Wv, Wo, tern, S);
    k_alpha<<<1, 64, 0, stream>>>(S);
    k_digx<<<4096, 256, 0, stream>>>(x, XD);
    k_proji8<<<dim3(32, 16, 3), 256, 0, stream>>>(XD, tern, bq, bk, bv, QD, KD, V, S);
    k_attn<<<dim3(SEQ / 64, BATCH * NHEADS), 256, 0, stream>>>(QD, KD, V, XD);
    k_oproji8<<<dim3(32, 16), 256, 0, stream>>>(XD, tern, bo, Z, S);
    k_scale<<<1, 1, 0, stream>>>(S);
    k_quant<<<4096, 256, 0, stream>>>(Z, S, out);
}

// Round 5
// 1120.968 us; speedup vs baseline: 3.7144x; 1.2762x over previous
//
#include <hip/hip_runtime.h>
#include <math.h>

#define DMODEL 1024
#define NHEADS 16
#define DHEAD  64
#define BATCH  2
#define SEQ    2048
#define NTOK   (BATCH*SEQ)            // 4096
#define WEL    (DMODEL*DMODEL)        // 1048576
#define PLANE  ((size_t)NTOK*DMODEL)  // 4,194,304 B per digit plane

typedef double v4d __attribute__((ext_vector_type(4)));
typedef int    v4i __attribute__((ext_vector_type(4)));

// ---------------- workspace layout (bytes) ----------------
// S | tern 4MB | XD row-major x digits (later y digits) 20MB
// | QDF (Q digit A-frags) 20MB | KDF (K digit B-frags) 20MB | VDF 20MB
// Z fp64 (32MB) overwrites QDF+KDF after attention.
#define OFF_TERN 4096
#define OFF_XD   (OFF_TERN + 4*WEL)            // 4,198,400
#define OFF_QDF  (OFF_XD  + 5*4194304)         // 25,169,920
#define OFF_KDF  (OFF_QDF + 20971520)          // 46,141,440
#define OFF_VDF  (OFF_KDF + 20971520)          // 67,112,960
#define WS_NEED  ((size_t)OFF_VDF + 20971520)  // 88,084,480

#define TWO36 68719476736.0   // 2^36

__global__ void k_zero_scalars(double* S) {
    if (threadIdx.x < 64) S[threadIdx.x] = 0.0;
}

__device__ __forceinline__ double block_reduce_sum(double v, double* red) {
    int tid = threadIdx.x;
    __syncthreads();
    red[tid] = v;
    __syncthreads();
    for (int s = 128; s > 0; s >>= 1) {
        if (tid < s) red[tid] += red[tid + s];
        __syncthreads();
    }
    return red[0];
}

__global__ __launch_bounds__(256) void k_abssum(
    const float* __restrict__ W0, const float* __restrict__ W1,
    const float* __restrict__ W2, const float* __restrict__ W3, double* S) {
    __shared__ double red[256];
    int w = blockIdx.y;
    const float* W = (w == 0) ? W0 : (w == 1) ? W1 : (w == 2) ? W2 : W3;
    double s = 0.0;
    for (int i = blockIdx.x * 256 + threadIdx.x; i < WEL; i += 256 * 256)
        s += fabs((double)W[i]);
    double bs = block_reduce_sum(s, red);
    if (threadIdx.x == 0) atomicAdd(&S[w], bs);
}

__global__ void k_delta(double* S) {
    int w = threadIdx.x;
    if (w < 4) S[16 + w] = 0.05 * S[w] / (double)WEL;
}

__global__ __launch_bounds__(256) void k_tern(
    const float* __restrict__ W0, const float* __restrict__ W1,
    const float* __restrict__ W2, const float* __restrict__ W3,
    signed char* __restrict__ tern, double* S) {
    __shared__ double red[256];
    int w = blockIdx.y;
    const float* W = (w == 0) ? W0 : (w == 1) ? W1 : (w == 2) ? W2 : W3;
    signed char* t = tern + (size_t)w * WEL;
    double delta = S[16 + w];
    double ms = 0.0, mc = 0.0;
    for (int i = blockIdx.x * 256 + threadIdx.x; i < WEL; i += 256 * 256) {
        float wv = W[i];
        double a = fabs((double)wv);
        bool m = a > delta;
        t[i] = m ? (wv > 0.0f ? (signed char)1 : (signed char)-1) : (signed char)0;
        if (m) { ms += a; mc += 1.0; }
    }
    double bms = block_reduce_sum(ms, red);
    double bmc = block_reduce_sum(mc, red);
    if (threadIdx.x == 0) { atomicAdd(&S[4 + w], bms); atomicAdd(&S[8 + w], bmc); }
}

__global__ void k_alpha(double* S) {
    int w = threadIdx.x;
    if (w < 4) S[12 + w] = S[4 + w] / fmax(S[8 + w], 1.0);
}

// ---------------- x -> 5 signed-i8 digit planes ----------------
__global__ __launch_bounds__(256) void k_digx(const float* __restrict__ x,
                                              signed char* __restrict__ XD) {
    int g = blockIdx.x * 256 + threadIdx.x;
    const int NG = NTOK * DMODEL / 4;
    if (g >= NG) return;
    float4 f = ((const float4*)x)[g];
    double vals[4] = {f.x, f.y, f.z, f.w};
    unsigned int p[5] = {0, 0, 0, 0, 0};
#pragma unroll
    for (int e = 0; e < 4; ++e) {
        long X = llrint(vals[e] * TWO36);
        const long LIM = (1L << 39) - 1;
        X = (X > LIM) ? LIM : (X < -LIM ? -LIM : X);
#pragma unroll
        for (int i = 0; i < 5; ++i) {
            signed char di = (signed char)X;
            X = (X - di) >> 8;
            p[i] |= ((unsigned int)(unsigned char)di) << (8 * e);
        }
    }
#pragma unroll
    for (int i = 0; i < 5; ++i)
        ((unsigned int*)(XD + (size_t)i * PLANE))[g] = p[i];
}

// ---------------- QKV projection: i8 MFMA; outputs digit-FRAG layouts --------------
// Q A-frag:  addr = ((bh*128 + rg)*5 + p)*1024 + kc*512 + lane*8 + e
// K B-frag:  addr = (bh*32+s5)*20480 + ((p*4 + ct)*2 + kc)*512 + lane*8 + e
// V B-frag (s-permuted ks=4*(s&15)+(s>>4)):
//            addr = (bh*32+s5)*20480 + ((p*4 + u)*2 + kc2)*512 + lane*8 + e
__global__ __launch_bounds__(256) void k_proji8(
    const signed char* __restrict__ XD, const signed char* __restrict__ tern,
    const float* __restrict__ bq, const float* __restrict__ bk,
    const float* __restrict__ bv,
    unsigned char* __restrict__ QDF, unsigned char* __restrict__ KDF,
    unsigned char* __restrict__ VDF, const double* __restrict__ S) {
    int w = blockIdx.z;
    const signed char* B = tern + (size_t)w * WEL;
    const float* bias = (w == 0) ? bq : (w == 1) ? bk : bv;
    double alpha = S[12 + w];

    __shared__ signed char As[128 * 144];
    __shared__ signed char Bs[64 * 144];

    int tid = threadIdx.x;
    int wv = tid >> 6, l = tid & 63, lm = l & 15, lk = l >> 4;
    int wy = wv >> 1, wx = wv & 1;
    int row0 = blockIdx.x * 128, col0 = blockIdx.y * 64;

    v4i zz4 = {0, 0, 0, 0};
    long ppa = (lk == 0) ? (long)lm : 0L;
    long ppb = (lk == 0) ? 1L : 0L;
    v4i rowv = __builtin_amdgcn_mfma_i32_16x16x32_i8(ppa, ppb, zz4, 0, 0, 0);
    v4i colv = __builtin_amdgcn_mfma_i32_16x16x32_i8(ppb, ppa, zz4, 0, 0, 0);
    int rowi[4];
#pragma unroll
    for (int j = 0; j < 4; ++j) rowi[j] = rowv[j];
    int coli = colv[0];

    v4d Facc[8];
#pragma unroll
    for (int t = 0; t < 8; ++t) Facc[t] = (v4d){0.0, 0.0, 0.0, 0.0};

    const double DW[5] = {0x1p-36, 0x1p-28, 0x1p-20, 0x1p-12, 0x1p-4};

    for (int d = 0; d < 5; ++d) {
        const signed char* Ad = XD + (size_t)d * PLANE;
        v4i Iacc[8];
#pragma unroll
        for (int t = 0; t < 8; ++t) Iacc[t] = (v4i){0, 0, 0, 0};

        for (int k0 = 0; k0 < DMODEL; k0 += 128) {
            __syncthreads();
            {
                int r = tid >> 1, hf = tid & 1;
                const int4* src = (const int4*)(Ad + (size_t)(row0 + r) * DMODEL + k0 + hf * 64);
                int4* dst = (int4*)(As + r * 144 + hf * 64);
                dst[0] = src[0]; dst[1] = src[1]; dst[2] = src[2]; dst[3] = src[3];
            }
            {
                int r = tid >> 2, q = tid & 3;
                const int4* src = (const int4*)(B + (size_t)(col0 + r) * DMODEL + k0 + q * 32);
                int4* dst = (int4*)(Bs + r * 144 + q * 32);
                dst[0] = src[0]; dst[1] = src[1];
            }
            __syncthreads();
#pragma unroll
            for (int ks = 0; ks < 4; ++ks) {
                long av[4], bv2[2];
#pragma unroll
                for (int mt = 0; mt < 4; ++mt)
                    av[mt] = *(const long*)(As + (wy * 64 + mt * 16 + lm) * 144 + ks * 32 + 8 * lk);
#pragma unroll
                for (int nt = 0; nt < 2; ++nt)
                    bv2[nt] = *(const long*)(Bs + (wx * 32 + nt * 16 + lm) * 144 + ks * 32 + 8 * lk);
#pragma unroll
                for (int mt = 0; mt < 4; ++mt)
#pragma unroll
                    for (int nt = 0; nt < 2; ++nt)
                        Iacc[mt * 2 + nt] = __builtin_amdgcn_mfma_i32_16x16x32_i8(
                            av[mt], bv2[nt], Iacc[mt * 2 + nt], 0, 0, 0);
            }
        }
        double wd = DW[d];
#pragma unroll
        for (int t = 0; t < 8; ++t)
#pragma unroll
            for (int j = 0; j < 4; ++j) Facc[t][j] += wd * (double)Iacc[t][j];
    }

    // epilogue: digitize into fragment layouts
#pragma unroll
    for (int t = 0; t < 8; ++t) {
#pragma unroll
        for (int j = 0; j < 4; ++j) {
            int rl = wy * 64 + (t >> 1) * 16 + rowi[j];
            int cl = wx * 32 + (t & 1) * 16 + coli;
            int n = row0 + rl, c = col0 + cl;
            double v = alpha * Facc[t][j] + (double)bias[c];
            long X = llrint(v * TWO36);
            const long LIM = (1L << 39) - 1;
            X = (X > LIM) ? LIM : (X < -LIM ? -LIM : X);
            int bh = ((n >> 11) << 4) + (c >> 6);
            int d = c & 63;
            int t2 = n & 2047;
            size_t base; size_t pstride;
            if (w == 0) {
                int rg = t2 >> 4, m = t2 & 15;
                int kc = d >> 5, k32 = d & 31, lkq = k32 >> 3, e = k32 & 7;
                base = ((size_t)(bh * 128 + rg) * 5) * 1024 + (size_t)kc * 512
                     + (16 * lkq + m) * 8 + e;
                pstride = 1024;
            } else if (w == 1) {
                int s5 = t2 >> 6, s64 = t2 & 63, ct = s64 >> 4, nn = s64 & 15;
                int kc = d >> 5, k32 = d & 31, lkq = k32 >> 3, e = k32 & 7;
                base = (size_t)(bh * 32 + s5) * 20480 + (size_t)(ct * 2 + kc) * 512
                     + (16 * lkq + nn) * 8 + e;
                pstride = 4096;
            } else {
                int s5 = t2 >> 6, s64 = t2 & 63;
                int ks = 4 * (s64 & 15) + (s64 >> 4);
                int kc2 = ks >> 5, k32 = ks & 31, lkq = k32 >> 3, e = k32 & 7;
                int u = d >> 4, lmv = d & 15;
                base = (size_t)(bh * 32 + s5) * 20480 + (size_t)(u * 2 + kc2) * 512
                     + (16 * lkq + lmv) * 8 + e;
                pstride = 4096;
            }
            unsigned char* P = (w == 0) ? QDF : (w == 1) ? KDF : VDF;
#pragma unroll
            for (int i = 0; i < 5; ++i) {
                signed char di = (signed char)X;
                X = (X - di) >> 8;
                P[base + (size_t)i * pstride] = di;
            }
        }
    }
}

// ---------------- all-i8 flash attention ----------------
// QK: A=Q digit frags (regs), B=K digit frags (LDS). PV: A=P digits (LDS, s-permuted),
// B=V digit frags (LDS). Exact i32/i64 digit accumulation, pairs i+j>=3.
__global__ __launch_bounds__(256, 2) void k_attn(
    const unsigned char* __restrict__ QDF, const unsigned char* __restrict__ KDF,
    const unsigned char* __restrict__ VDF, signed char* __restrict__ YD) {
    __shared__ unsigned long KBs[2560];   // [p][ct][kc][lane]
    __shared__ unsigned long VBs[2560];   // [p][u][kc2][lane]
    __shared__ signed char  PD[4 * 5 * 16 * 72];  // [w][p][m][72]

    int tid = threadIdx.x;
    int w = tid >> 6, l = tid & 63;
    int lm = l & 15, lk = l >> 4;
    int bh = blockIdx.y;
    int t0 = blockIdx.x * 64;
    size_t nrow0 = (size_t)(bh >> 4) * SEQ;
    int cbase = (bh & 15) * 64;

    v4i zz4 = {0, 0, 0, 0};
    long ppa = (lk == 0) ? (long)lm : 0L;
    long ppb = (lk == 0) ? 1L : 0L;
    v4i rowv = __builtin_amdgcn_mfma_i32_16x16x32_i8(ppa, ppb, zz4, 0, 0, 0);
    v4i colv = __builtin_amdgcn_mfma_i32_16x16x32_i8(ppb, ppa, zz4, 0, 0, 0);
    int rowi[4];
#pragma unroll
    for (int j = 0; j < 4; ++j) rowi[j] = rowv[j];
    int coli = colv[0];

    // Q A-frags in registers (10 x b64)
    unsigned long qf[5][2];
    {
        size_t rg5 = ((size_t)bh * 128 + (t0 >> 4) + w) * 5;
#pragma unroll
        for (int p = 0; p < 5; ++p)
#pragma unroll
            for (int kc = 0; kc < 2; ++kc)
                qf[p][kc] = *(const unsigned long*)(QDF + (rg5 + p) * 1024 + kc * 512 + l * 8);
    }

    double m_[4], l_[4];
    v4d Yacc[4];
#pragma unroll
    for (int j = 0; j < 4; j++) { m_[j] = -INFINITY; l_[j] = 0.0; }
#pragma unroll
    for (int u = 0; u < 4; u++) Yacc[u] = (v4d){0.0, 0.0, 0.0, 0.0};

    size_t kvbase = (size_t)bh * 32 * 20480;

    for (int s5 = 0; s5 < 32; ++s5) {
        __syncthreads();
        {
            const int4* gk = (const int4*)(KDF + kvbase + (size_t)s5 * 20480);
            const int4* gv = (const int4*)(VDF + kvbase + (size_t)s5 * 20480);
            int4* dk = (int4*)KBs;
            int4* dv = (int4*)VBs;
#pragma unroll
            for (int it = 0; it < 5; ++it) {
                dk[it * 256 + tid] = gk[it * 256 + tid];
                dv[it * 256 + tid] = gv[it * 256 + tid];
            }
        }
        __syncthreads();

        double sv[4][4];   // [c][j]: scores, then p

        // ---- QK^T in two c-halves ----
#pragma unroll
        for (int h2 = 0; h2 < 2; ++h2) {
            v4i lev[6][2];
#pragma unroll
            for (int L = 0; L < 6; ++L) { lev[L][0] = zz4; lev[L][1] = zz4; }
#pragma unroll
            for (int kc = 0; kc < 2; ++kc)
#pragma unroll
                for (int j = 0; j < 5; ++j) {
                    unsigned long b0 = KBs[((j * 4 + h2 * 2 + 0) * 2 + kc) * 64 + l];
                    unsigned long b1 = KBs[((j * 4 + h2 * 2 + 1) * 2 + kc) * 64 + l];
#pragma unroll
                    for (int i = 0; i < 5; ++i)
                        if (i + j >= 3) {
                            lev[i + j - 3][0] = __builtin_amdgcn_mfma_i32_16x16x32_i8(
                                (long)qf[i][kc], (long)b0, lev[i + j - 3][0], 0, 0, 0);
                            lev[i + j - 3][1] = __builtin_amdgcn_mfma_i32_16x16x32_i8(
                                (long)qf[i][kc], (long)b1, lev[i + j - 3][1], 0, 0, 0);
                        }
                }
#pragma unroll
            for (int cc = 0; cc < 2; ++cc)
#pragma unroll
                for (int j2 = 0; j2 < 4; ++j2) {
                    long acc = (long)lev[5][cc][j2];
#pragma unroll
                    for (int L = 4; L >= 0; --L) acc = (acc << 8) + (long)lev[L][cc][j2];
                    sv[h2 * 2 + cc][j2] = (double)acc * 0x1p-51;  // *2^-48 * 0.125
                }
        }

        // ---- online softmax ----
#pragma unroll
        for (int j2 = 0; j2 < 4; ++j2) {
            double mt = fmax(fmax(sv[0][j2], sv[1][j2]), fmax(sv[2][j2], sv[3][j2]));
            mt = fmax(mt, __shfl_xor(mt, 1));
            mt = fmax(mt, __shfl_xor(mt, 2));
            mt = fmax(mt, __shfl_xor(mt, 4));
            mt = fmax(mt, __shfl_xor(mt, 8));
            double mn = fmax(m_[j2], mt);
            double cc_ = exp(m_[j2] - mn);
            m_[j2] = mn;
            l_[j2] *= cc_;
#pragma unroll
            for (int u = 0; u < 4; ++u) Yacc[u][j2] *= cc_;
            double rs = 0.0;
#pragma unroll
            for (int c = 0; c < 4; ++c) {
                double p = exp(sv[c][j2] - mn);
                sv[c][j2] = p;
                rs += p;
            }
            rs += __shfl_xor(rs, 1);
            rs += __shfl_xor(rs, 2);
            rs += __shfl_xor(rs, 4);
            rs += __shfl_xor(rs, 8);
            l_[j2] += rs;
        }

        // ---- digitize P into PD (per-wave region; ks = 4*coli + c) ----
#pragma unroll
        for (int j2 = 0; j2 < 4; ++j2) {
            long X[4];
#pragma unroll
            for (int c = 0; c < 4; ++c) X[c] = llrint(sv[c][j2] * TWO36);
            int rbase = (w * 5 * 16 + rowi[j2]) * 72 + 4 * coli;
#pragma unroll
            for (int p = 0; p < 5; ++p) {
                unsigned int word = 0;
#pragma unroll
                for (int c = 0; c < 4; ++c) {
                    signed char di = (signed char)X[c];
                    X[c] = (X[c] - di) >> 8;
                    word |= ((unsigned int)(unsigned char)di) << (8 * c);
                }
                *(unsigned int*)(PD + rbase + p * 16 * 72) = word;
            }
        }

        // ---- PV in two u-halves ----
#pragma unroll
        for (int u2 = 0; u2 < 2; ++u2) {
            v4i lev[6][2];
#pragma unroll
            for (int L = 0; L < 6; ++L) { lev[L][0] = zz4; lev[L][1] = zz4; }
#pragma unroll
            for (int kc2 = 0; kc2 < 2; ++kc2) {
                long pa5[5];
#pragma unroll
                for (int i = 0; i < 5; ++i)
                    pa5[i] = *(const long*)(PD + ((w * 5 + i) * 16 + lm) * 72 + 32 * kc2 + 8 * lk);
#pragma unroll
                for (int j = 0; j < 5; ++j) {
                    unsigned long b0 = VBs[((j * 4 + u2 * 2 + 0) * 2 + kc2) * 64 + l];
                    unsigned long b1 = VBs[((j * 4 + u2 * 2 + 1) * 2 + kc2) * 64 + l];
#pragma unroll
                    for (int i = 0; i < 5; ++i)
                        if (i + j >= 3) {
                            lev[i + j - 3][0] = __builtin_amdgcn_mfma_i32_16x16x32_i8(
                                pa5[i], (long)b0, lev[i + j - 3][0], 0, 0, 0);
                            lev[i + j - 3][1] = __builtin_amdgcn_mfma_i32_16x16x32_i8(
                                pa5[i], (long)b1, lev[i + j - 3][1], 0, 0, 0);
                        }
                }
            }
#pragma unroll
            for (int uu = 0; uu < 2; ++uu)
#pragma unroll
                for (int j2 = 0; j2 < 4; ++j2) {
                    long acc = (long)lev[5][uu][j2];
#pragma unroll
                    for (int L = 4; L >= 0; --L) acc = (acc << 8) + (long)lev[L][uu][j2];
                    Yacc[u2 * 2 + uu][j2] += (double)acc * 0x1p-48;
                }
        }
    }

    // ---- epilogue: y -> digit planes (row-major, for oproj) ----
#pragma unroll
    for (int j2 = 0; j2 < 4; ++j2) {
        double inv = 1.0 / l_[j2];
        size_t n = nrow0 + t0 + 16 * w + rowi[j2];
#pragma unroll
        for (int u = 0; u < 4; ++u) {
            double y = Yacc[u][j2] * inv;
            int c = cbase + 16 * u + coli;
            long X = llrint(y * TWO36);
            const long LIM = (1L << 39) - 1;
            X = (X > LIM) ? LIM : (X < -LIM ? -LIM : X);
#pragma unroll
            for (int i = 0; i < 5; ++i) {
                signed char di = (signed char)X;
                X = (X - di) >> 8;
                YD[(size_t)i * PLANE + n * DMODEL + c] = di;
            }
        }
    }
}

// ---------------- output projection via i8 MFMA; z -> Z fp64 + global max ----------
__global__ __launch_bounds__(256) void k_oproji8(
    const signed char* __restrict__ YD, const signed char* __restrict__ tern,
    const float* __restrict__ bo, double* __restrict__ Z, double* __restrict__ S) {
    const signed char* B = tern + 3 * (size_t)WEL;
    double alpha = S[15];

    __shared__ signed char As[128 * 144];
    __shared__ signed char Bs[64 * 144];
    __shared__ double redm[256];

    int tid = threadIdx.x;
    int wv = tid >> 6, l = tid & 63, lm = l & 15, lk = l >> 4;
    int wy = wv >> 1, wx = wv & 1;
    int row0 = blockIdx.x * 128, col0 = blockIdx.y * 64;

    v4i zz4 = {0, 0, 0, 0};
    long ppa = (lk == 0) ? (long)lm : 0L;
    long ppb = (lk == 0) ? 1L : 0L;
    v4i rowv = __builtin_amdgcn_mfma_i32_16x16x32_i8(ppa, ppb, zz4, 0, 0, 0);
    v4i colv = __builtin_amdgcn_mfma_i32_16x16x32_i8(ppb, ppa, zz4, 0, 0, 0);
    int rowi[4];
#pragma unroll
    for (int j = 0; j < 4; ++j) rowi[j] = rowv[j];
    int coli = colv[0];

    v4d Facc[8];
#pragma unroll
    for (int t = 0; t < 8; ++t) Facc[t] = (v4d){0.0, 0.0, 0.0, 0.0};

    const double DW[5] = {0x1p-36, 0x1p-28, 0x1p-20, 0x1p-12, 0x1p-4};

    for (int d = 0; d < 5; ++d) {
        const signed char* Ad = YD + (size_t)d * PLANE;
        v4i Iacc[8];
#pragma unroll
        for (int t = 0; t < 8; ++t) Iacc[t] = (v4i){0, 0, 0, 0};

        for (int k0 = 0; k0 < DMODEL; k0 += 128) {
            __syncthreads();
            {
                int r = tid >> 1, hf = tid & 1;
                const int4* src = (const int4*)(Ad + (size_t)(row0 + r) * DMODEL + k0 + hf * 64);
                int4* dst = (int4*)(As + r * 144 + hf * 64);
                dst[0] = src[0]; dst[1] = src[1]; dst[2] = src[2]; dst[3] = src[3];
            }
            {
                int r = tid >> 2, q = tid & 3;
                const int4* src = (const int4*)(B + (size_t)(col0 + r) * DMODEL + k0 + q * 32);
                int4* dst = (int4*)(Bs + r * 144 + q * 32);
                dst[0] = src[0]; dst[1] = src[1];
            }
            __syncthreads();
#pragma unroll
            for (int ks = 0; ks < 4; ++ks) {
                long av[4], bv2[2];
#pragma unroll
                for (int mt = 0; mt < 4; ++mt)
                    av[mt] = *(const long*)(As + (wy * 64 + mt * 16 + lm) * 144 + ks * 32 + 8 * lk);
#pragma unroll
                for (int nt = 0; nt < 2; ++nt)
                    bv2[nt] = *(const long*)(Bs + (wx * 32 + nt * 16 + lm) * 144 + ks * 32 + 8 * lk);
#pragma unroll
                for (int mt = 0; mt < 4; ++mt)
#pragma unroll
                    for (int nt = 0; nt < 2; ++nt)
                        Iacc[mt * 2 + nt] = __builtin_amdgcn_mfma_i32_16x16x32_i8(
                            av[mt], bv2[nt], Iacc[mt * 2 + nt], 0, 0, 0);
            }
        }
        double wd = DW[d];
#pragma unroll
        for (int t = 0; t < 8; ++t)
#pragma unroll
            for (int j = 0; j < 4; ++j) Facc[t][j] += wd * (double)Iacc[t][j];
    }

    double mx = 0.0;
#pragma unroll
    for (int t = 0; t < 8; ++t) {
#pragma unroll
        for (int j = 0; j < 4; ++j) {
            int rl = wy * 64 + (t >> 1) * 16 + rowi[j];
            int cl = wx * 32 + (t & 1) * 16 + coli;
            int n = row0 + rl, c = col0 + cl;
            double v = alpha * Facc[t][j] + (double)bo[c];
            Z[(size_t)n * DMODEL + c] = v;
            mx = fmax(mx, fabs(v));
        }
    }
    redm[tid] = mx;
    __syncthreads();
    for (int s = 128; s > 0; s >>= 1) {
        if (tid < s) redm[tid] = fmax(redm[tid], redm[tid + s]);
        __syncthreads();
    }
    if (tid == 0)
        atomicMax((unsigned long long*)&S[20],
                  (unsigned long long)__double_as_longlong(redm[0]));
}

__global__ void k_scale(double* S) {
    unsigned long long bits = *((unsigned long long*)&S[20]);
    double mx = __longlong_as_double((long long)bits);
    S[21] = fmax(mx / 7.0, 1e-8);
}

__global__ __launch_bounds__(256) void k_quant(const double* __restrict__ Z,
                                               const double* __restrict__ S,
                                               float* __restrict__ out) {
    double scale = S[21];
    double inv = 1.0 / scale;
    int i = blockIdx.x * 256 + threadIdx.x;
    const int n = NTOK * DMODEL;
    for (; i < n; i += gridDim.x * 256) {
        double r = rint(Z[i] * inv);
        r = fmin(fmax(r, -7.0), 7.0);
        out[i] = (float)(r * scale);
    }
}

extern "C" void kernel_launch(void* const* d_in, const int* in_sizes, int n_in,
                              void* d_out, int out_size, void* d_ws, size_t ws_size,
                              hipStream_t stream) {
    if (ws_size < WS_NEED) return;

    const float* x  = (const float*)d_in[0];
    const float* Wq = (const float*)d_in[1];
    const float* bq = (const float*)d_in[2];
    const float* Wk = (const float*)d_in[3];
    const float* bk = (const float*)d_in[4];
    const float* Wv = (const float*)d_in[5];
    const float* bv = (const float*)d_in[6];
    const float* Wo = (const float*)d_in[7];
    const float* bo = (const float*)d_in[8];
    float* out = (float*)d_out;

    double* S = (double*)d_ws;
    signed char* tern = (signed char*)d_ws + OFF_TERN;
    signed char* XD = (signed char*)d_ws + OFF_XD;        // x digits; later y digits
    unsigned char* QDF = (unsigned char*)d_ws + OFF_QDF;
    unsigned char* KDF = (unsigned char*)d_ws + OFF_KDF;
    unsigned char* VDF = (unsigned char*)d_ws + OFF_VDF;
    double* Z = (double*)((char*)d_ws + OFF_QDF);         // frees after attention

    k_zero_scalars<<<1, 64, 0, stream>>>(S);
    k_abssum<<<dim3(256, 4), 256, 0, stream>>>(Wq, Wk, Wv, Wo, S);
    k_delta<<<1, 64, 0, stream>>>(S);
    k_tern<<<dim3(256, 4), 256, 0, stream>>>(Wq, Wk, Wv, Wo, tern, S);
    k_alpha<<<1, 64, 0, stream>>>(S);
    k_digx<<<4096, 256, 0, stream>>>(x, XD);
    k_proji8<<<dim3(32, 16, 3), 256, 0, stream>>>(XD, tern, bq, bk, bv, QDF, KDF, VDF, S);
    k_attn<<<dim3(SEQ / 64, BATCH * NHEADS), 256, 0, stream>>>(QDF, KDF, VDF, XD);
    k_oproji8<<<dim3(32, 16), 256, 0, stream>>>(XD, tern, bo, Z, S);
    k_scale<<<1, 1, 0, stream>>>(S);
    k_quant<<<4096, 256, 0, stream>>>(Z, S, out);
}